// Round 4
// baseline (1495.571 us; speedup 1.0000x reference)
//
#include <hip/hip_runtime.h>
#include <stdint.h>

// TopK SAE forward, MI355X/gfx950.
// bf16-MFMA approximate encoder (fp16 Z scratch) -> fused per-row kernel:
// ballot binary-search candidate select (bit-identical to 1024-bin histogram,
// margin 0.015) -> exact fp64 recompute of ~77 candidates/row -> true top-64
// (index tie-break) -> zero+scatter+sparse-decode with bf16 W_decT.
//
// R1: enc_gemm 256x256-tile, BK=32, 8-wave pipeline (quad-buffered LDS,
//     counted vmcnt(8), XOR-swizzle via pre-swizzled global source, setprio,
//     XCD swizzle).
// R2: select+exact+decode fused into one per-row kernel; histogram replaced
//     by ballot binary search (no LDS atomics).
// R3: Zh moved to row-local slot inside Z (stride 2*N_LAT halves) — no
//     cross-block aliasing.
// R4: fused-kernel scheduling: Z-zero stores hoisted to overlap the fp64
//     gather phase (they previously serialized at the end); candidate gather
//     2-way unrolled per wave (halves serial L3-latency depth); decode uses
//     dual accumulators + 2 rows/iter for deeper load pipelining.

#define M_BATCH 8192
#define K_DIM   1024
#define N_LAT   16384
#define ZH_STRIDE (2 * N_LAT)   // halves per Zh row (row-local aliasing with Z)
#define TOPK    64
#define CAND_CAP 256
#define MARGIN  0.015f

typedef float f32x4 __attribute__((ext_vector_type(4)));
typedef unsigned int u32x4 __attribute__((ext_vector_type(4)));
typedef short s16x8 __attribute__((ext_vector_type(8)));
typedef unsigned short u16x8 __attribute__((ext_vector_type(8)));

typedef __attribute__((address_space(3))) void       lds_void;
typedef const __attribute__((address_space(1))) void glb_void;

__device__ __forceinline__ void async_copy16(const void* g, void* l) {
    __builtin_amdgcn_global_load_lds((glb_void*)g, (lds_void*)l, 16, 0, 0);
}

__device__ __forceinline__ unsigned short f2bf(float f) {
    uint32_t u = __float_as_uint(f);
    uint32_t r = (u + 0x7FFFu + ((u >> 16) & 1u)) >> 16;   // RNE
    return (unsigned short)r;
}
__device__ __forceinline__ float bf2f(unsigned short h) {
    return __uint_as_float(((uint32_t)h) << 16);
}
__device__ __forceinline__ unsigned short f2h(float f) {
    _Float16 h = (_Float16)f;
    unsigned short u;
    __builtin_memcpy(&u, &h, 2);
    return u;
}
__device__ __forceinline__ float h2f(unsigned short u) {
    _Float16 h;
    __builtin_memcpy(&h, &u, 2);
    return (float)h;
}

// ---------------- K0a: fp32 -> bf16 conversion ----------------
__global__ void to_bf16(const float4* __restrict__ src, unsigned short* __restrict__ dst,
                        int nvec) {
    int i = blockIdx.x * blockDim.x + threadIdx.x;
    if (i < nvec) {
        float4 f = src[i];
        ushort4 o;
        o.x = f2bf(f.x); o.y = f2bf(f.y); o.z = f2bf(f.z); o.w = f2bf(f.w);
        *(ushort4*)(dst + (size_t)i * 4) = o;
    }
}

// ---------------- K0b: W_dec [1024,16384] fp32 -> W_decT [16384,1024] bf16 ----------------
__global__ void transpose_wdec(const float* __restrict__ Wd, unsigned short* __restrict__ WdT) {
    __shared__ float tile[64][65];
    int bj = blockIdx.x;
    int bi = blockIdx.y;
    int t = threadIdx.x;
    int tj = t & 63, ti4 = t >> 6;
    #pragma unroll
    for (int rr = 0; rr < 16; rr++) {
        int i = ti4 * 16 + rr;
        tile[i][tj] = Wd[(size_t)(bi * 64 + i) * N_LAT + bj * 64 + tj];
    }
    __syncthreads();
    int ti = t & 63, tj4 = t >> 6;
    #pragma unroll
    for (int rr = 0; rr < 16; rr++) {
        int j = tj4 * 16 + rr;
        WdT[(size_t)(bj * 64 + j) * K_DIM + bi * 64 + ti] = f2bf(tile[ti][j]);
    }
}

// ---------------- K1: bf16 MFMA encoder GEMM, 256x256 tile, pipelined ----------------
// LDS buffer layout (per 32KB buffer): A [256 rows][4 units of 16B], then B same
// at +16384. Unit u of row r stored at u ^ ((r>>1)&3)  (involution; applied by
// pre-swizzling the global source; global_load_lds dest stays linear).
template<bool STAGE>
__device__ __forceinline__ void ktile256(
        const char* smemc, unsigned bufOff,
        unsigned aRowBase, unsigned bRowBase,
        f32x4 (&acc)[8][4],
        const unsigned short* sA0, const unsigned short* sA1,
        const unsigned short* sB0, const unsigned short* sB1,
        char* db)
{
    const char* bufA = smemc + bufOff;
    const char* bufB = bufA + 16384;
    if constexpr (STAGE) {
        async_copy16(sA0, db);
        async_copy16(sB0, db + 16384);
    }
    s16x8 bfr[4], afr[4];
    #pragma unroll
    for (int ni = 0; ni < 4; ni++)
        bfr[ni] = *(const s16x8*)(bufB + bRowBase + ni * 1024);
    #pragma unroll
    for (int mi = 0; mi < 4; mi++)
        afr[mi] = *(const s16x8*)(bufA + aRowBase + mi * 1024);
    __builtin_amdgcn_s_setprio(1);
    #pragma unroll
    for (int mi = 0; mi < 4; mi++)
        #pragma unroll
        for (int ni = 0; ni < 4; ni++)
            acc[mi][ni] = __builtin_amdgcn_mfma_f32_16x16x32_bf16(
                afr[mi], bfr[ni], acc[mi][ni], 0, 0, 0);
    __builtin_amdgcn_s_setprio(0);
    if constexpr (STAGE) {
        async_copy16(sA1, db + 8192);
        async_copy16(sB1, db + 24576);
    }
    #pragma unroll
    for (int mi = 0; mi < 4; mi++)
        afr[mi] = *(const s16x8*)(bufA + aRowBase + (4 + mi) * 1024);
    __builtin_amdgcn_s_setprio(1);
    #pragma unroll
    for (int mi = 0; mi < 4; mi++)
        #pragma unroll
        for (int ni = 0; ni < 4; ni++)
            acc[4 + mi][ni] = __builtin_amdgcn_mfma_f32_16x16x32_bf16(
                afr[mi], bfr[ni], acc[4 + mi][ni], 0, 0, 0);
    __builtin_amdgcn_s_setprio(0);
}

__global__ __launch_bounds__(512, 2) void enc_gemm256(
        const unsigned short* __restrict__ A,
        const unsigned short* __restrict__ B,
        const float* __restrict__ b_enc,
        unsigned short* __restrict__ Zh) {
    __shared__ __align__(128) char smemc[131072];   // 4 bufs x (A 16KB + B 16KB)
    int tid = threadIdx.x;
    int w = tid >> 6, l = tid & 63;
    int wm = w >> 2, wn = w & 3;            // 2 x 4 waves, wave tile 128x64
    int lm = l & 15, q = l >> 4;

    // bijective XCD swizzle (2048 % 8 == 0): each XCD owns an 8-col band of bn
    int orig = blockIdx.x;
    int swz = (orig & 7) * 256 + (orig >> 3);
    int bm = (swz & 255) >> 3;              // 0..31
    int bn = (swz >> 8) * 8 + (swz & 7);    // 0..63

    const unsigned short* gA = A + (size_t)bm * 256 * K_DIM;
    const unsigned short* gB = B + (size_t)bn * 256 * K_DIM;

    // staging: thread t loads unit (r0, t&3) [inst0] and (r0+128, t&3) [inst1];
    // pre-swizzled global k-unit = (t&3) ^ ((r0>>1)&3)
    int r0 = tid >> 2;
    int ul = (tid & 3) ^ ((tid >> 3) & 3);
    size_t off0 = (size_t)r0 * K_DIM + (size_t)ul * 8;
    size_t off1 = off0 + (size_t)128 * K_DIM;

    // fragment read byte offsets (within buffer); row&3-swizzle folds to lane const
    unsigned swzL = (unsigned)((q ^ ((lm >> 1) & 3)) * 16);
    unsigned aRowBase = (unsigned)((wm * 128 + lm) * 64) + swzL;
    unsigned bRowBase = (unsigned)((wn * 64 + lm) * 64) + swzL;

    f32x4 acc[8][4];
    #pragma unroll
    for (int i = 0; i < 8; i++)
        #pragma unroll
        for (int j = 0; j < 4; j++) acc[i][j] = (f32x4)0.0f;

    // prologue: stage tiles 0,1,2 (tile-ordered issue: 4 insts per tile)
    #pragma unroll
    for (int tt = 0; tt < 3; tt++) {
        char* db = smemc + tt * 32768 + tid * 16;
        async_copy16(gA + off0 + tt * 32, db);
        async_copy16(gB + off0 + tt * 32, db + 16384);
        async_copy16(gA + off1 + tt * 32, db + 8192);
        async_copy16(gB + off1 + tt * 32, db + 24576);
    }
    asm volatile("s_waitcnt vmcnt(8)" ::: "memory");   // tile 0 ready; 1,2 in flight
    __builtin_amdgcn_s_barrier();
    asm volatile("" ::: "memory");

    const unsigned short* sA0 = gA + off0 + 96;        // tile 3 sources
    const unsigned short* sA1 = gA + off1 + 96;
    const unsigned short* sB0 = gB + off0 + 96;
    const unsigned short* sB1 = gB + off1 + 96;

    // main loop: compute tile t (buf t&3), stage tile t+3 (buf (t+3)&3).
    // boundary: need tile t+1 complete -> leave tiles t+2,t+3 in flight = vmcnt(8)
    #pragma unroll 4
    for (int t = 0; t < 28; ++t) {
        unsigned bufOff = (unsigned)(t & 3) * 32768u;
        char* db = smemc + (unsigned)((t + 3) & 3) * 32768u + tid * 16;
        ktile256<true>(smemc, bufOff, aRowBase, bRowBase, acc, sA0, sA1, sB0, sB1, db);
        sA0 += 32; sA1 += 32; sB0 += 32; sB1 += 32;
        asm volatile("s_waitcnt vmcnt(8)" ::: "memory");
        __builtin_amdgcn_s_barrier();
        asm volatile("" ::: "memory");
    }
    {   // t = 28: stages tile 31 -> buf 3
        char* db = smemc + 3u * 32768u + tid * 16;
        ktile256<true>(smemc, 0u, aRowBase, bRowBase, acc, sA0, sA1, sB0, sB1, db);
        asm volatile("s_waitcnt vmcnt(8)" ::: "memory");
        __builtin_amdgcn_s_barrier();
        asm volatile("" ::: "memory");
    }
    // t = 29
    ktile256<false>(smemc, 1u * 32768u, aRowBase, bRowBase, acc, sA0, sA1, sB0, sB1, nullptr);
    asm volatile("s_waitcnt vmcnt(4)" ::: "memory");
    __builtin_amdgcn_s_barrier();
    asm volatile("" ::: "memory");
    // t = 30
    ktile256<false>(smemc, 2u * 32768u, aRowBase, bRowBase, acc, sA0, sA1, sB0, sB1, nullptr);
    asm volatile("s_waitcnt vmcnt(0)" ::: "memory");
    __builtin_amdgcn_s_barrier();
    asm volatile("" ::: "memory");
    // t = 31
    ktile256<false>(smemc, 3u * 32768u, aRowBase, bRowBase, acc, sA0, sA1, sB0, sB1, nullptr);

    // epilogue: bias + fp16 store (row stride ZH_STRIDE halves: Zh row r lives
    // in the first half of Z row r's 64KB slot — row-local aliasing only)
    size_t gm0 = (size_t)bm * 256 + wm * 128;
    size_t gn0 = (size_t)bn * 256 + wn * 64;
    #pragma unroll
    for (int ni = 0; ni < 4; ni++) {
        size_t gn = gn0 + ni * 16 + lm;
        float bv = b_enc[gn];
        #pragma unroll
        for (int mi = 0; mi < 8; mi++) {
            size_t gmb = gm0 + mi * 16 + q * 4;
            #pragma unroll
            for (int r = 0; r < 4; r++)
                Zh[(gmb + r) * (size_t)ZH_STRIDE + gn] = f2h(acc[mi][ni][r] + bv);
        }
    }
}

// ---------------- K2: fused select (ballot binary search) + exact fp64 topk
//                       + zero/scatter/decode, one block per row ----------------
// Cut semantics are bit-identical to the old 1024-bin histogram:
//   b = max{ j in [0,1023] : count(f >= j/64) >= 64 },  cut = b/64 - MARGIN.
// Probe thresholds j/64 are exactly representable in fp16, so fp16 compares
// reproduce the f32 histogram binning exactly.
__global__ __launch_bounds__(256) void fused_sel_dec(
        const unsigned short* __restrict__ Zh,
        const float* __restrict__ x, const float* __restrict__ W,
        const float* __restrict__ b_enc,
        const unsigned short* __restrict__ WdT,
        const float* __restrict__ b_dec,
        float* __restrict__ recon, float* __restrict__ Z) {
    __shared__ float xs[K_DIM];
    __shared__ double vals[CAND_CAP];
    __shared__ int ns[CAND_CAP];
    __shared__ int is[TOPK];
    __shared__ float vs[TOPK];
    __shared__ int wred[10][4];
    __shared__ int s_cn;

    int r = blockIdx.x;
    int t = threadIdx.x;
    int w = t >> 6, l = t & 63;

    // x row -> LDS (consumed by exact phase)
    ((float4*)xs)[t] = ((const float4*)(x + (size_t)r * K_DIM))[t];
    if (t == 0) s_cn = 0;

    // Zh row -> registers (32 KB / block, 128 B / thread); row-local slot,
    // so the later Z-row zeroing only clobbers data this block already holds.
    const u32x4* zg = (const u32x4*)(Zh + (size_t)r * ZH_STRIDE);
    u16x8 v[8];
    #pragma unroll
    for (int it = 0; it < 8; it++) {
        u32x4 raw = __builtin_nontemporal_load(&zg[t + it * 256]);
        __builtin_memcpy(&v[it], &raw, 16);
    }

    // 10-step binary search: no atomics, count via v_cmp_ge_f16 + ballot popcount
    int lo = 0, hi = 1023;
    #pragma unroll
    for (int iter = 0; iter < 10; iter++) {
        int mid = (lo + hi + 1) >> 1;
        _Float16 T = (_Float16)((float)mid * (1.0f / 64.0f));
        int c = 0;
        #pragma unroll
        for (int it = 0; it < 8; it++)
            #pragma unroll
            for (int j = 0; j < 8; j++) {
                _Float16 h;
                unsigned short u = v[it][j];
                __builtin_memcpy(&h, &u, 2);
                c += (int)__popcll(__ballot(h >= T));
            }
        if (l == 0) wred[iter][w] = c;
        __syncthreads();
        int tot = wred[iter][0] + wred[iter][1] + wred[iter][2] + wred[iter][3];
        if (tot >= TOPK) lo = mid; else hi = mid - 1;
    }
    float cut = (float)lo * (1.0f / 64.0f) - MARGIN;

    // candidate collection (~77/row, capped at 256)
    #pragma unroll
    for (int it = 0; it < 8; it++)
        #pragma unroll
        for (int j = 0; j < 8; j++) {
            float f = h2f(v[it][j]);
            if (f >= cut) {
                int p = atomicAdd(&s_cn, 1);
                if (p < CAND_CAP) ns[p] = (t + it * 256) * 8 + j;
            }
        }
    __syncthreads();
    int n_c = min(s_cn, CAND_CAP);

    // zero this row's z NOW (streaming stores): the 64KB of writes drain
    // underneath the gather phase below (no barrier until it ends). This
    // clobbers only this row's own Zh slot, already held in registers; all
    // threads' Zh loads completed at the search barriers above.
    f32x4* zr4 = (f32x4*)(Z + (size_t)r * N_LAT);
    {
        f32x4 z4 = (f32x4)0.0f;
        #pragma unroll
        for (int it = 0; it < 16; it++)
            __builtin_nontemporal_store(z4, &zr4[t + it * 256]);
    }

    // exact fp64 recompute of candidates, 2 per wave concurrently
    for (int c = w; c < n_c; c += 8) {
        int cB = c + 4;
        bool hasB = (cB < n_c);
        const float4* wrA = (const float4*)(W + (size_t)ns[c] * K_DIM);
        const float4* wrB = hasB ? (const float4*)(W + (size_t)ns[cB] * K_DIM) : wrA;
        double sA = 0.0, sB = 0.0;
        #pragma unroll
        for (int i = 0; i < 4; i++) {
            float4 wvA = wrA[l + i * 64];
            float4 wvB = wrB[l + i * 64];
            float4 xv = ((const float4*)xs)[l + i * 64];
            sA += (double)xv.x * wvA.x + (double)xv.y * wvA.y
                + (double)xv.z * wvA.z + (double)xv.w * wvA.w;
            sB += (double)xv.x * wvB.x + (double)xv.y * wvB.y
                + (double)xv.z * wvB.z + (double)xv.w * wvB.w;
        }
        for (int o = 32; o > 0; o >>= 1) {
            sA += __shfl_down(sA, o, 64);
            sB += __shfl_down(sB, o, 64);
        }
        if (l == 0) {
            vals[c] = sA + (double)b_enc[ns[c]];
            if (hasB) vals[cB] = sB + (double)b_enc[ns[cB]];
        }
    }
    __syncthreads();

    // rank (lax.top_k tie-break: value desc, index asc)
    if (t < n_c) {
        double vv = vals[t];
        int n = ns[t];
        int rank = 0;
        for (int j = 0; j < n_c; j++) {
            double vj = vals[j];
            if (vj > vv || (vj == vv && ns[j] < n)) rank++;
        }
        if (rank < TOPK) {
            is[rank] = n;
            vs[rank] = (float)(vv > 0.0 ? vv : 0.0);
        }
    }
    __syncthreads();   // drains any remaining zero stores; is/vs visible

    // scatter the 64 selected values into the (now zeroed) Z row
    if (t < TOPK) Z[(size_t)r * N_LAT + is[t]] = vs[t];

    // sparse decode: 2 rows per iteration, dual accumulators
    f32x4 acc0 = (f32x4)0.0f, acc1 = (f32x4)0.0f;
    #pragma unroll 4
    for (int j = 0; j < TOPK; j += 2) {
        const unsigned short* wr0 = WdT + (size_t)is[j] * K_DIM;
        const unsigned short* wr1 = WdT + (size_t)is[j + 1] * K_DIM;
        float v0 = vs[j], v1 = vs[j + 1];
        ushort4 w40 = *(const ushort4*)(wr0 + 4 * t);
        ushort4 w41 = *(const ushort4*)(wr1 + 4 * t);
        acc0.x += v0 * bf2f(w40.x);
        acc0.y += v0 * bf2f(w40.y);
        acc0.z += v0 * bf2f(w40.z);
        acc0.w += v0 * bf2f(w40.w);
        acc1.x += v1 * bf2f(w41.x);
        acc1.y += v1 * bf2f(w41.y);
        acc1.z += v1 * bf2f(w41.z);
        acc1.w += v1 * bf2f(w41.w);
    }
    f32x4 acc = acc0 + acc1;
    f32x4 bd = *(const f32x4*)(b_dec + 4 * t);
    acc += bd;
    __builtin_nontemporal_store(acc, (f32x4*)(recon + (size_t)r * K_DIM + 4 * t));
}

// ---------------- launch ----------------
extern "C" void kernel_launch(void* const* d_in, const int* in_sizes, int n_in,
                              void* d_out, int out_size, void* d_ws, size_t ws_size,
                              hipStream_t stream) {
    const float* x     = (const float*)d_in[0];
    const float* W_enc = (const float*)d_in[1];
    const float* b_enc = (const float*)d_in[2];
    const float* W_dec = (const float*)d_in[3];
    const float* b_dec = (const float*)d_in[4];
    float* recon = (float*)d_out;
    float* Z     = recon + (size_t)M_BATCH * K_DIM;     // fp32 z output region
    unsigned short* Zh = (unsigned short*)Z;            // fp16 scratch, row r at
                                                        // halves offset r*ZH_STRIDE

    char* ws = (char*)d_ws;
    unsigned short* Wh  = (unsigned short*)(ws);                 // 33,554,432 B
    unsigned short* xh  = (unsigned short*)(ws + 33554432);      // 16,777,216 B
    unsigned short* WdT = (unsigned short*)(ws + 50331648);      // 33,554,432 B

    to_bf16<<<(N_LAT * K_DIM / 4 + 255) / 256, 256, 0, stream>>>(
        (const float4*)W_enc, Wh, N_LAT * K_DIM / 4);
    to_bf16<<<(M_BATCH * K_DIM / 4 + 255) / 256, 256, 0, stream>>>(
        (const float4*)x, xh, M_BATCH * K_DIM / 4);
    transpose_wdec<<<dim3(N_LAT / 64, K_DIM / 64), 256, 0, stream>>>(W_dec, WdT);

    enc_gemm256<<<(M_BATCH / 256) * (N_LAT / 256), 512, 0, stream>>>(xh, Wh, b_enc, Zh);

    fused_sel_dec<<<M_BATCH, 256, 0, stream>>>(Zh, x, W_enc, b_enc, WdT, b_dec, recon, Z);
}

// Round 5
// 1422.112 us; speedup vs baseline: 1.0517x; 1.0517x over previous
//
#include <hip/hip_runtime.h>
#include <stdint.h>

// TopK SAE forward, MI355X/gfx950.
// bf16-MFMA approximate encoder (fp16 Z scratch) -> fused per-row kernel:
// ballot binary-search candidate select (bit-identical to 1024-bin histogram,
// margin 0.015) -> exact fp64 recompute of ~77 candidates/row -> true top-64
// (index tie-break) -> zero+scatter+sparse-decode with bf16 W_decT.
//
// R1: enc_gemm 256x256-tile, BK=32, 8-wave pipeline (quad-buffered LDS,
//     counted vmcnt(8), XOR-swizzle via pre-swizzled global source, setprio,
//     XCD swizzle).
// R2: select+exact+decode fused into one per-row kernel; histogram replaced
//     by ballot binary search (no LDS atomics).
// R3: Zh moved to row-local slot inside Z (stride 2*N_LAT halves) — no
//     cross-block aliasing.
// R4 (REVERTED in R5): gather unroll + zero hoist cost occupancy (53->43%),
//     fused 587->601. Fused body restored to R3.
// R5: GEMM epilogue rewritten — was 128 scalar 2B global stores per thread
//     (134M store instrs/dispatch ~ 220us issue floor; explains R1's null
//     result). Now: fragments -> LDS (128KB, XOR-swizzled, conflict-free)
//     -> 16 coalesced global_store_dwordx4 per thread. Zh bit-identical.

#define M_BATCH 8192
#define K_DIM   1024
#define N_LAT   16384
#define ZH_STRIDE (2 * N_LAT)   // halves per Zh row (row-local aliasing with Z)
#define TOPK    64
#define CAND_CAP 256
#define MARGIN  0.015f

typedef float f32x4 __attribute__((ext_vector_type(4)));
typedef unsigned int u32x4 __attribute__((ext_vector_type(4)));
typedef short s16x8 __attribute__((ext_vector_type(8)));
typedef unsigned short u16x8 __attribute__((ext_vector_type(8)));

typedef __attribute__((address_space(3))) void       lds_void;
typedef const __attribute__((address_space(1))) void glb_void;

__device__ __forceinline__ void async_copy16(const void* g, void* l) {
    __builtin_amdgcn_global_load_lds((glb_void*)g, (lds_void*)l, 16, 0, 0);
}

__device__ __forceinline__ unsigned short f2bf(float f) {
    uint32_t u = __float_as_uint(f);
    uint32_t r = (u + 0x7FFFu + ((u >> 16) & 1u)) >> 16;   // RNE
    return (unsigned short)r;
}
__device__ __forceinline__ float bf2f(unsigned short h) {
    return __uint_as_float(((uint32_t)h) << 16);
}
__device__ __forceinline__ unsigned short f2h(float f) {
    _Float16 h = (_Float16)f;
    unsigned short u;
    __builtin_memcpy(&u, &h, 2);
    return u;
}
__device__ __forceinline__ float h2f(unsigned short u) {
    _Float16 h;
    __builtin_memcpy(&h, &u, 2);
    return (float)h;
}

// ---------------- K0a: fp32 -> bf16 conversion ----------------
__global__ void to_bf16(const float4* __restrict__ src, unsigned short* __restrict__ dst,
                        int nvec) {
    int i = blockIdx.x * blockDim.x + threadIdx.x;
    if (i < nvec) {
        float4 f = src[i];
        ushort4 o;
        o.x = f2bf(f.x); o.y = f2bf(f.y); o.z = f2bf(f.z); o.w = f2bf(f.w);
        *(ushort4*)(dst + (size_t)i * 4) = o;
    }
}

// ---------------- K0b: W_dec [1024,16384] fp32 -> W_decT [16384,1024] bf16 ----------------
__global__ void transpose_wdec(const float* __restrict__ Wd, unsigned short* __restrict__ WdT) {
    __shared__ float tile[64][65];
    int bj = blockIdx.x;
    int bi = blockIdx.y;
    int t = threadIdx.x;
    int tj = t & 63, ti4 = t >> 6;
    #pragma unroll
    for (int rr = 0; rr < 16; rr++) {
        int i = ti4 * 16 + rr;
        tile[i][tj] = Wd[(size_t)(bi * 64 + i) * N_LAT + bj * 64 + tj];
    }
    __syncthreads();
    int ti = t & 63, tj4 = t >> 6;
    #pragma unroll
    for (int rr = 0; rr < 16; rr++) {
        int j = tj4 * 16 + rr;
        WdT[(size_t)(bj * 64 + j) * K_DIM + bi * 64 + ti] = f2bf(tile[ti][j]);
    }
}

// ---------------- K1: bf16 MFMA encoder GEMM, 256x256 tile, pipelined ----------------
// LDS buffer layout (per 32KB buffer): A [256 rows][4 units of 16B], then B same
// at +16384. Unit u of row r stored at u ^ ((r>>1)&3)  (involution; applied by
// pre-swizzling the global source; global_load_lds dest stays linear).
template<bool STAGE>
__device__ __forceinline__ void ktile256(
        const char* smemc, unsigned bufOff,
        unsigned aRowBase, unsigned bRowBase,
        f32x4 (&acc)[8][4],
        const unsigned short* sA0, const unsigned short* sA1,
        const unsigned short* sB0, const unsigned short* sB1,
        char* db)
{
    const char* bufA = smemc + bufOff;
    const char* bufB = bufA + 16384;
    if constexpr (STAGE) {
        async_copy16(sA0, db);
        async_copy16(sB0, db + 16384);
    }
    s16x8 bfr[4], afr[4];
    #pragma unroll
    for (int ni = 0; ni < 4; ni++)
        bfr[ni] = *(const s16x8*)(bufB + bRowBase + ni * 1024);
    #pragma unroll
    for (int mi = 0; mi < 4; mi++)
        afr[mi] = *(const s16x8*)(bufA + aRowBase + mi * 1024);
    __builtin_amdgcn_s_setprio(1);
    #pragma unroll
    for (int mi = 0; mi < 4; mi++)
        #pragma unroll
        for (int ni = 0; ni < 4; ni++)
            acc[mi][ni] = __builtin_amdgcn_mfma_f32_16x16x32_bf16(
                afr[mi], bfr[ni], acc[mi][ni], 0, 0, 0);
    __builtin_amdgcn_s_setprio(0);
    if constexpr (STAGE) {
        async_copy16(sA1, db + 8192);
        async_copy16(sB1, db + 24576);
    }
    #pragma unroll
    for (int mi = 0; mi < 4; mi++)
        afr[mi] = *(const s16x8*)(bufA + aRowBase + (4 + mi) * 1024);
    __builtin_amdgcn_s_setprio(1);
    #pragma unroll
    for (int mi = 0; mi < 4; mi++)
        #pragma unroll
        for (int ni = 0; ni < 4; ni++)
            acc[4 + mi][ni] = __builtin_amdgcn_mfma_f32_16x16x32_bf16(
                afr[mi], bfr[ni], acc[4 + mi][ni], 0, 0, 0);
    __builtin_amdgcn_s_setprio(0);
}

__global__ __launch_bounds__(512, 2) void enc_gemm256(
        const unsigned short* __restrict__ A,
        const unsigned short* __restrict__ B,
        const float* __restrict__ b_enc,
        unsigned short* __restrict__ Zh) {
    __shared__ __align__(128) char smemc[131072];   // 4 bufs x (A 16KB + B 16KB)
    int tid = threadIdx.x;
    int w = tid >> 6, l = tid & 63;
    int wm = w >> 2, wn = w & 3;            // 2 x 4 waves, wave tile 128x64
    int lm = l & 15, q = l >> 4;

    // bijective XCD swizzle (2048 % 8 == 0): each XCD owns an 8-col band of bn
    int orig = blockIdx.x;
    int swz = (orig & 7) * 256 + (orig >> 3);
    int bm = (swz & 255) >> 3;              // 0..31
    int bn = (swz >> 8) * 8 + (swz & 7);    // 0..63

    const unsigned short* gA = A + (size_t)bm * 256 * K_DIM;
    const unsigned short* gB = B + (size_t)bn * 256 * K_DIM;

    // staging: thread t loads unit (r0, t&3) [inst0] and (r0+128, t&3) [inst1];
    // pre-swizzled global k-unit = (t&3) ^ ((r0>>1)&3)
    int r0 = tid >> 2;
    int ul = (tid & 3) ^ ((tid >> 3) & 3);
    size_t off0 = (size_t)r0 * K_DIM + (size_t)ul * 8;
    size_t off1 = off0 + (size_t)128 * K_DIM;

    // fragment read byte offsets (within buffer); row&3-swizzle folds to lane const
    unsigned swzL = (unsigned)((q ^ ((lm >> 1) & 3)) * 16);
    unsigned aRowBase = (unsigned)((wm * 128 + lm) * 64) + swzL;
    unsigned bRowBase = (unsigned)((wn * 64 + lm) * 64) + swzL;

    f32x4 acc[8][4];
    #pragma unroll
    for (int i = 0; i < 8; i++)
        #pragma unroll
        for (int j = 0; j < 4; j++) acc[i][j] = (f32x4)0.0f;

    // prologue: stage tiles 0,1,2 (tile-ordered issue: 4 insts per tile)
    #pragma unroll
    for (int tt = 0; tt < 3; tt++) {
        char* db = smemc + tt * 32768 + tid * 16;
        async_copy16(gA + off0 + tt * 32, db);
        async_copy16(gB + off0 + tt * 32, db + 16384);
        async_copy16(gA + off1 + tt * 32, db + 8192);
        async_copy16(gB + off1 + tt * 32, db + 24576);
    }
    asm volatile("s_waitcnt vmcnt(8)" ::: "memory");   // tile 0 ready; 1,2 in flight
    __builtin_amdgcn_s_barrier();
    asm volatile("" ::: "memory");

    const unsigned short* sA0 = gA + off0 + 96;        // tile 3 sources
    const unsigned short* sA1 = gA + off1 + 96;
    const unsigned short* sB0 = gB + off0 + 96;
    const unsigned short* sB1 = gB + off1 + 96;

    // main loop: compute tile t (buf t&3), stage tile t+3 (buf (t+3)&3).
    // boundary: need tile t+1 complete -> leave tiles t+2,t+3 in flight = vmcnt(8)
    #pragma unroll 4
    for (int t = 0; t < 28; ++t) {
        unsigned bufOff = (unsigned)(t & 3) * 32768u;
        char* db = smemc + (unsigned)((t + 3) & 3) * 32768u + tid * 16;
        ktile256<true>(smemc, bufOff, aRowBase, bRowBase, acc, sA0, sA1, sB0, sB1, db);
        sA0 += 32; sA1 += 32; sB0 += 32; sB1 += 32;
        asm volatile("s_waitcnt vmcnt(8)" ::: "memory");
        __builtin_amdgcn_s_barrier();
        asm volatile("" ::: "memory");
    }
    {   // t = 28: stages tile 31 -> buf 3
        char* db = smemc + 3u * 32768u + tid * 16;
        ktile256<true>(smemc, 0u, aRowBase, bRowBase, acc, sA0, sA1, sB0, sB1, db);
        asm volatile("s_waitcnt vmcnt(8)" ::: "memory");
        __builtin_amdgcn_s_barrier();
        asm volatile("" ::: "memory");
    }
    // t = 29
    ktile256<false>(smemc, 1u * 32768u, aRowBase, bRowBase, acc, sA0, sA1, sB0, sB1, nullptr);
    asm volatile("s_waitcnt vmcnt(4)" ::: "memory");
    __builtin_amdgcn_s_barrier();
    asm volatile("" ::: "memory");
    // t = 30
    ktile256<false>(smemc, 2u * 32768u, aRowBase, bRowBase, acc, sA0, sA1, sB0, sB1, nullptr);
    asm volatile("s_waitcnt vmcnt(0)" ::: "memory");
    __builtin_amdgcn_s_barrier();
    asm volatile("" ::: "memory");
    // t = 31
    ktile256<false>(smemc, 3u * 32768u, aRowBase, bRowBase, acc, sA0, sA1, sB0, sB1, nullptr);

    // ---- R5 epilogue: bias + f2h -> LDS transpose -> coalesced dwordx4 stores.
    // LDS layout: half(row,col) at byte (row*512 + col*2) ^ (((row>>2)&3)<<5).
    // Write:  fixed (ni,mi,r): lanes = 16 cols x 4 q-rows; q-XOR makes the 4
    //         row-groups hit disjoint bank octets -> 32 banks x 2 lanes (free).
    // Read:   16B/thread contiguous; XOR flips bits 5-6 (16B-aligned safe).
    // Zh bytes/addresses/values identical to the previous scalar epilogue.
    __syncthreads();
    size_t gm0b = (size_t)bm * 256;
    size_t gn0b = (size_t)bn * 256;
    #pragma unroll
    for (int ni = 0; ni < 4; ni++) {
        int colr = wn * 64 + ni * 16 + lm;              // block-relative col
        float bv = b_enc[gn0b + colr];
        #pragma unroll
        for (int mi = 0; mi < 8; mi++) {
            #pragma unroll
            for (int r = 0; r < 4; r++) {
                int row = wm * 128 + mi * 16 + q * 4 + r;
                unsigned byte = (unsigned)(row * 512 + colr * 2);
                byte ^= ((unsigned)(row >> 2) & 3u) << 5;
                *(unsigned short*)(smemc + byte) = f2h(acc[mi][ni][r] + bv);
            }
        }
    }
    __syncthreads();
    {
        unsigned rowrr = (unsigned)tid >> 5;            // 0..15
        unsigned unit = (unsigned)tid & 31;             // 0..31 (16B units)
        #pragma unroll
        for (int i = 0; i < 16; i++) {
            unsigned row = (unsigned)i * 16 + rowrr;
            unsigned byte = row * 512 + unit * 16;
            byte ^= ((row >> 2) & 3u) << 5;
            u32x4 vv = *(const u32x4*)(smemc + byte);
            *(u32x4*)(Zh + (gm0b + row) * (size_t)ZH_STRIDE + gn0b + unit * 8) = vv;
        }
    }
}

// ---------------- K2: fused select (ballot binary search) + exact fp64 topk
//                       + zero/scatter/decode, one block per row ----------------
// Cut semantics are bit-identical to the old 1024-bin histogram:
//   b = max{ j in [0,1023] : count(f >= j/64) >= 64 },  cut = b/64 - MARGIN.
// Probe thresholds j/64 are exactly representable in fp16, so fp16 compares
// reproduce the f32 histogram binning exactly.
__global__ __launch_bounds__(256) void fused_sel_dec(
        const unsigned short* __restrict__ Zh,
        const float* __restrict__ x, const float* __restrict__ W,
        const float* __restrict__ b_enc,
        const unsigned short* __restrict__ WdT,
        const float* __restrict__ b_dec,
        float* __restrict__ recon, float* __restrict__ Z) {
    __shared__ float xs[K_DIM];
    __shared__ double vals[CAND_CAP];
    __shared__ int ns[CAND_CAP];
    __shared__ int is[TOPK];
    __shared__ float vs[TOPK];
    __shared__ int wred[10][4];
    __shared__ int s_cn;

    int r = blockIdx.x;
    int t = threadIdx.x;
    int w = t >> 6, l = t & 63;

    // x row -> LDS (consumed by exact phase)
    ((float4*)xs)[t] = ((const float4*)(x + (size_t)r * K_DIM))[t];
    if (t == 0) s_cn = 0;

    // Zh row -> registers (32 KB / block, 128 B / thread); row-local slot,
    // so the later Z-row zeroing only clobbers data this block already holds.
    const u32x4* zg = (const u32x4*)(Zh + (size_t)r * ZH_STRIDE);
    u16x8 v[8];
    #pragma unroll
    for (int it = 0; it < 8; it++) {
        u32x4 raw = __builtin_nontemporal_load(&zg[t + it * 256]);
        __builtin_memcpy(&v[it], &raw, 16);
    }

    // 10-step binary search: no atomics, count via v_cmp_ge_f16 + ballot popcount
    int lo = 0, hi = 1023;
    #pragma unroll
    for (int iter = 0; iter < 10; iter++) {
        int mid = (lo + hi + 1) >> 1;
        _Float16 T = (_Float16)((float)mid * (1.0f / 64.0f));
        int c = 0;
        #pragma unroll
        for (int it = 0; it < 8; it++)
            #pragma unroll
            for (int j = 0; j < 8; j++) {
                _Float16 h;
                unsigned short u = v[it][j];
                __builtin_memcpy(&h, &u, 2);
                c += (int)__popcll(__ballot(h >= T));
            }
        if (l == 0) wred[iter][w] = c;
        __syncthreads();
        int tot = wred[iter][0] + wred[iter][1] + wred[iter][2] + wred[iter][3];
        if (tot >= TOPK) lo = mid; else hi = mid - 1;
    }
    float cut = (float)lo * (1.0f / 64.0f) - MARGIN;

    // candidate collection (~77/row, capped at 256)
    #pragma unroll
    for (int it = 0; it < 8; it++)
        #pragma unroll
        for (int j = 0; j < 8; j++) {
            float f = h2f(v[it][j]);
            if (f >= cut) {
                int p = atomicAdd(&s_cn, 1);
                if (p < CAND_CAP) ns[p] = (t + it * 256) * 8 + j;
            }
        }
    __syncthreads();
    int n_c = min(s_cn, CAND_CAP);

    // exact fp64 recompute of candidates
    for (int c = w; c < n_c; c += 4) {
        const float4* wr = (const float4*)(W + (size_t)ns[c] * K_DIM);
        double s = 0.0;
        #pragma unroll
        for (int i = 0; i < 4; i++) {
            float4 wv = wr[l + i * 64];
            float4 xv = ((const float4*)xs)[l + i * 64];
            s += (double)xv.x * wv.x + (double)xv.y * wv.y
               + (double)xv.z * wv.z + (double)xv.w * wv.w;
        }
        for (int o = 32; o > 0; o >>= 1) s += __shfl_down(s, o, 64);
        if (l == 0) vals[c] = s + (double)b_enc[ns[c]];
    }
    __syncthreads();

    // rank (lax.top_k tie-break: value desc, index asc)
    if (t < n_c) {
        double vv = vals[t];
        int n = ns[t];
        int rank = 0;
        for (int j = 0; j < n_c; j++) {
            double vj = vals[j];
            if (vj > vv || (vj == vv && ns[j] < n)) rank++;
        }
        if (rank < TOPK) {
            is[rank] = n;
            vs[rank] = (float)(vv > 0.0 ? vv : 0.0);
        }
    }
    __syncthreads();

    // zero this row's z (streaming stores), then scatter.
    // This overwrites this row's own Zh slot only (already in registers).
    f32x4* zr4 = (f32x4*)(Z + (size_t)r * N_LAT);
    f32x4 z4 = (f32x4)0.0f;
    #pragma unroll
    for (int it = 0; it < 16; it++)
        __builtin_nontemporal_store(z4, &zr4[t + it * 256]);
    __syncthreads();
    if (t < TOPK) Z[(size_t)r * N_LAT + is[t]] = vs[t];

    // sparse decode
    f32x4 acc = (f32x4)0.0f;
    #pragma unroll 4
    for (int j = 0; j < TOPK; j++) {
        const unsigned short* wr = WdT + (size_t)is[j] * K_DIM;
        float vj = vs[j];
        ushort4 w4 = *(const ushort4*)(wr + 4 * t);
        acc.x += vj * bf2f(w4.x);
        acc.y += vj * bf2f(w4.y);
        acc.z += vj * bf2f(w4.z);
        acc.w += vj * bf2f(w4.w);
    }
    f32x4 bd = *(const f32x4*)(b_dec + 4 * t);
    acc += bd;
    __builtin_nontemporal_store(acc, (f32x4*)(recon + (size_t)r * K_DIM + 4 * t));
}

// ---------------- launch ----------------
extern "C" void kernel_launch(void* const* d_in, const int* in_sizes, int n_in,
                              void* d_out, int out_size, void* d_ws, size_t ws_size,
                              hipStream_t stream) {
    const float* x     = (const float*)d_in[0];
    const float* W_enc = (const float*)d_in[1];
    const float* b_enc = (const float*)d_in[2];
    const float* W_dec = (const float*)d_in[3];
    const float* b_dec = (const float*)d_in[4];
    float* recon = (float*)d_out;
    float* Z     = recon + (size_t)M_BATCH * K_DIM;     // fp32 z output region
    unsigned short* Zh = (unsigned short*)Z;            // fp16 scratch, row r at
                                                        // halves offset r*ZH_STRIDE

    char* ws = (char*)d_ws;
    unsigned short* Wh  = (unsigned short*)(ws);                 // 33,554,432 B
    unsigned short* xh  = (unsigned short*)(ws + 33554432);      // 16,777,216 B
    unsigned short* WdT = (unsigned short*)(ws + 50331648);      // 33,554,432 B

    to_bf16<<<(N_LAT * K_DIM / 4 + 255) / 256, 256, 0, stream>>>(
        (const float4*)W_enc, Wh, N_LAT * K_DIM / 4);
    to_bf16<<<(M_BATCH * K_DIM / 4 + 255) / 256, 256, 0, stream>>>(
        (const float4*)x, xh, M_BATCH * K_DIM / 4);
    transpose_wdec<<<dim3(N_LAT / 64, K_DIM / 64), 256, 0, stream>>>(W_dec, WdT);

    enc_gemm256<<<(M_BATCH / 256) * (N_LAT / 256), 512, 0, stream>>>(xh, Wh, b_enc, Zh);

    fused_sel_dec<<<M_BATCH, 256, 0, stream>>>(Zh, x, W_enc, b_enc, WdT, b_dec, recon, Z);
}